// Round 5
// baseline (9578.239 us; speedup 1.0000x reference)
//
#include <hip/hip_runtime.h>

#define T_TOK 4096
#define HID   2048
#define NH    32
#define HD    128
#define PP    4096

typedef unsigned short u16;
typedef unsigned int   u32;
typedef __attribute__((ext_vector_type(8))) short short8;
typedef __attribute__((ext_vector_type(4))) float floatx4;

__device__ __forceinline__ float b2f(u16 u) {
  union { u32 i; float f; } x; x.i = ((u32)u) << 16; return x.f;
}
__device__ __forceinline__ u16 f2b(float f) {
  u32 x = __float_as_uint(f);
  u32 r = (x + 0x7fffu + ((x >> 16) & 1u)) >> 16;
  return (u16)r;
}
__device__ __forceinline__ float sigmoidf_(float x) { return 1.f / (1.f + expf(-x)); }

// ---------------- GEMM: C[M,N]bf16 = A[M,K] * B[K,N]f32 via bf16 MFMA ----------------
// ABF16: A stored bf16 (exact as stored). ASPL/BSPL: split fp32 operand into hi+lo bf16
// (hi*hi + hi*lo + lo*hi = fp32-quality). 64x64 tile, 4 waves, 2x2 mfma 16x16x32.
template<int ABF16, int ASPL, int BSPL>
__global__ __launch_bounds__(256)
void gemm_k(const void* __restrict__ Av, const float* __restrict__ B,
            u16* __restrict__ C, int M, int N, int K) {
  __shared__ u16 As[ASPL + 1][64][40];
  __shared__ u16 Bs[BSPL + 1][32][72];
  const int tid  = threadIdx.x;
  const int lane = tid & 63;
  const int wave = tid >> 6;
  const long bm = (long)blockIdx.y * 64;
  const long bn = (long)blockIdx.x * 64;
  const int wm = (wave >> 1) * 32;
  const int wn = (wave & 1) * 32;
  const int ar = tid >> 2, ac = (tid & 3) * 8;   // A stage: 64 rows x 4 chunks of 8
  const int br = tid >> 3, bc = (tid & 7) * 8;   // B stage: 32 rows x 8 chunks of 8
  const int q = lane >> 4, r = lane & 15;
  floatx4 acc[2][2];
#pragma unroll
  for (int i = 0; i < 2; ++i)
#pragma unroll
    for (int j = 0; j < 2; ++j) acc[i][j] = (floatx4)0.f;

  for (int k0 = 0; k0 < K; k0 += 32) {
    u16 ahi[8], alo[8], bhi[8], blo[8];
    if (ABF16) {
      const u16* A = (const u16*)Av;
      *(float4*)ahi = *(const float4*)(A + (bm + ar) * (long)K + k0 + ac);
    } else {
      const float* A = (const float*)Av;
      const float* ap = A + (bm + ar) * (long)K + k0 + ac;
#pragma unroll
      for (int e = 0; e < 8; ++e) {
        float x = ap[e];
        u16 hh = f2b(x);
        ahi[e] = hh;
        if (ASPL) alo[e] = f2b(x - b2f(hh));
      }
    }
    {
      const float* bp = B + (long)(k0 + br) * N + bn + bc;
#pragma unroll
      for (int e = 0; e < 8; ++e) {
        float x = bp[e];
        u16 hh = f2b(x);
        bhi[e] = hh;
        if (BSPL) blo[e] = f2b(x - b2f(hh));
      }
    }
    __syncthreads();
    *(float4*)&As[0][ar][ac] = *(float4*)ahi;
    *(float4*)&Bs[0][br][bc] = *(float4*)bhi;
    if (ASPL) *(float4*)&As[ASPL][ar][ac] = *(float4*)alo;
    if (BSPL) *(float4*)&Bs[BSPL][br][bc] = *(float4*)blo;
    __syncthreads();
    short8 afh[2], afl[2], bfh[2], bfl[2];
#pragma unroll
    for (int i = 0; i < 2; ++i) {
      afh[i] = *(const short8*)&As[0][wm + i * 16 + r][q * 8];
      if (ASPL) afl[i] = *(const short8*)&As[ASPL][wm + i * 16 + r][q * 8];
    }
#pragma unroll
    for (int i = 0; i < 2; ++i) {
      short8 th, tl;
#pragma unroll
      for (int j = 0; j < 8; ++j) {
        th[j] = (short)Bs[0][q * 8 + j][wn + i * 16 + r];
        if (BSPL) tl[j] = (short)Bs[BSPL][q * 8 + j][wn + i * 16 + r];
      }
      bfh[i] = th;
      if (BSPL) bfl[i] = tl;
    }
#pragma unroll
    for (int i = 0; i < 2; ++i)
#pragma unroll
      for (int j = 0; j < 2; ++j) {
        acc[i][j] = __builtin_amdgcn_mfma_f32_16x16x32_bf16(afh[i], bfh[j], acc[i][j], 0, 0, 0);
        if (BSPL) acc[i][j] = __builtin_amdgcn_mfma_f32_16x16x32_bf16(afh[i], bfl[j], acc[i][j], 0, 0, 0);
        if (ASPL) acc[i][j] = __builtin_amdgcn_mfma_f32_16x16x32_bf16(afl[i], bfh[j], acc[i][j], 0, 0, 0);
      }
  }
  // C/D layout: col = lane&15, row = (lane>>4)*4 + e
#pragma unroll
  for (int i = 0; i < 2; ++i)
#pragma unroll
    for (int j = 0; j < 2; ++j) {
      long col = bn + wn + j * 16 + r;
#pragma unroll
      for (int e = 0; e < 4; ++e) {
        long row = bm + wm + i * 16 + q * 4 + e;
        C[row * N + col] = f2b(acc[i][j][e]);
      }
    }
}

// ---------------- beta = 2*sigmoid(hs @ Wb)  [T,32] f32 ----------------
__global__ __launch_bounds__(256)
void beta_k(const float* __restrict__ hs, const float* __restrict__ Wb, float* __restrict__ beta) {
  int t = blockIdx.x * 8 + (threadIdx.x >> 5);
  int h = threadIdx.x & 31;
  const float* hrow = hs + (long)t * HID;
  float acc = 0.f;
  for (int k = 0; k < HID; ++k)
    acc += hrow[k] * Wb[k * NH + h];
  beta[t * NH + h] = 2.f * sigmoidf_(acc);
}

// ---- x = -5*sigmoid(exp(A_log[h]) * (g1pre + dt_bias)) in place bf16 (log-domain decay) ----
__global__ __launch_bounds__(256)
void expg_k(u16* __restrict__ g1, const float* __restrict__ dtb, const float* __restrict__ Alog) {
  int idx = blockIdx.x * 256 + threadIdx.x;
  int p = idx & (PP - 1);
  int h = p >> 7;
  float g = b2f(g1[idx]) + dtb[p];
  float a = expf(Alog[h]);
  g1[idx] = f2b(-5.f * sigmoidf_(a * g));
}

// ---------------- fused conv+silu + gated delta-rule scan ----------------
// One wave per (head, v-column). Lane owns k-channels {2*lane, 2*lane+1}.
// Inputs are RAW projection outputs (bf16); causal conv(K=4)+SiLU computed in fp32
// via 3-deep register history. Decay read log-domain (bf16 x, eg=exp(x) in fp32).
// o overwrites prev in place (element [t,h,vc] touched only by wave (h,vc)).
__global__ __launch_bounds__(256)
void scan_k(const u16* __restrict__ preq, const u16* __restrict__ prek,
            u16* __restrict__ prev, const u16* __restrict__ egx,
            const float* __restrict__ beta,
            const float* __restrict__ cq, const float* __restrict__ ck,
            const float* __restrict__ cv) {
  int wid  = blockIdx.x * 4 + (threadIdx.x >> 6);  // h*128 + vc
  int lane = threadIdx.x & 63;
  int h = wid >> 7, vc = wid & 127;
  int c0  = h * HD + 2 * lane;   // q/k channel pair
  int cv0 = h * HD + vc;         // v channel (wave-uniform)
  float qw[4][2], kw[4][2], vw[4];
#pragma unroll
  for (int j = 0; j < 4; ++j) {
    qw[j][0] = cq[c0 * 4 + j];       qw[j][1] = cq[(c0 + 1) * 4 + j];
    kw[j][0] = ck[c0 * 4 + j];       kw[j][1] = ck[(c0 + 1) * 4 + j];
    vw[j]    = cv[cv0 * 4 + j];
  }
  const u32* q32 = (const u32*)preq;
  const u32* k32 = (const u32*)prek;
  const u32* x32 = (const u32*)egx;
  float hq[3][2] = {}, hk[3][2] = {}, hv[3] = {};
  float Sx = 0.f, Sy = 0.f;
  const float qscale = 0.08838834764831845f;  // HD^-0.5
  for (int t = 0; t < T_TOK; ++t) {
    int rb = t * (PP / 2) + h * 64 + lane;
    u32 qr = q32[rb], kr = k32[rb], xr = x32[rb];
    float vraw = b2f(prev[t * PP + cv0]);
    float bt = beta[t * NH + h];
    float qx = b2f((u16)(qr & 0xffff)), qy = b2f((u16)(qr >> 16));
    float kx = b2f((u16)(kr & 0xffff)), ky = b2f((u16)(kr >> 16));
    float xx = b2f((u16)(xr & 0xffff)), xy = b2f((u16)(xr >> 16));
    // causal conv (w[3]*x[t] + w[2]*x[t-1] + w[1]*x[t-2] + w[0]*x[t-3])
    float cq0 = qw[3][0] * qx + qw[2][0] * hq[0][0] + qw[1][0] * hq[1][0] + qw[0][0] * hq[2][0];
    float cq1 = qw[3][1] * qy + qw[2][1] * hq[0][1] + qw[1][1] * hq[1][1] + qw[0][1] * hq[2][1];
    float ck0 = kw[3][0] * kx + kw[2][0] * hk[0][0] + kw[1][0] * hk[1][0] + kw[0][0] * hk[2][0];
    float ck1 = kw[3][1] * ky + kw[2][1] * hk[0][1] + kw[1][1] * hk[1][1] + kw[0][1] * hk[2][1];
    float cvv = vw[3] * vraw + vw[2] * hv[0] + vw[1] * hv[1] + vw[0] * hv[2];
    hq[2][0] = hq[1][0]; hq[1][0] = hq[0][0]; hq[0][0] = qx;
    hq[2][1] = hq[1][1]; hq[1][1] = hq[0][1]; hq[0][1] = qy;
    hk[2][0] = hk[1][0]; hk[1][0] = hk[0][0]; hk[0][0] = kx;
    hk[2][1] = hk[1][1]; hk[1][1] = hk[0][1]; hk[0][1] = ky;
    hv[2] = hv[1]; hv[1] = hv[0]; hv[0] = vraw;
    float qv0 = cq0 * sigmoidf_(cq0) * qscale;
    float qv1 = cq1 * sigmoidf_(cq1) * qscale;
    float kv0 = ck0 * sigmoidf_(ck0);
    float kv1 = ck1 * sigmoidf_(ck1);
    float vv  = cvv * sigmoidf_(cvv);
    // recurrence
    Sx *= expf(xx); Sy *= expf(xy);
    float pr = kv0 * Sx + kv1 * Sy;
#pragma unroll
    for (int m = 1; m < 64; m <<= 1) pr += __shfl_xor(pr, m, 64);
    float u = bt * (vv - pr);
    Sx += kv0 * u; Sy += kv1 * u;
    float o = qv0 * Sx + qv1 * Sy;
#pragma unroll
    for (int m = 1; m < 64; m <<= 1) o += __shfl_xor(o, m, 64);
    if (lane == 0) prev[t * PP + cv0] = f2b(o);
  }
}

// ---------------- rinv[t,h] = rsqrt(mean(o^2) + eps) ----------------
__global__ __launch_bounds__(256)
void rms_k(const u16* __restrict__ ob, float* __restrict__ rinv) {
  int wid  = blockIdx.x * 4 + (threadIdx.x >> 6);  // t*32 + h
  int lane = threadIdx.x & 63;
  u32 o2 = ((const u32*)ob)[(long)wid * 64 + lane];
  float ox = b2f((u16)(o2 & 0xffff)), oy = b2f((u16)(o2 >> 16));
  float ss = ox * ox + oy * oy;
#pragma unroll
  for (int m = 1; m < 64; m <<= 1) ss += __shfl_xor(ss, m, 64);
  if (lane == 0) rinv[wid] = rsqrtf(ss * (1.f / 128.f) + 1e-5f);
}

// ---------------- final GEMM with fused gated-RMSNorm A-staging ----------------
// A_eff[t,c] = o[t,c]*rinv[t,c>>7]*wn[c&127]*sigmoid(g2[t,c]); C = A_eff @ Wo, fp32 out.
__global__ __launch_bounds__(256)
void gemm_final_k(const u16* __restrict__ ob, const u16* __restrict__ g2,
                  const float* __restrict__ rinv, const float* __restrict__ wn,
                  const float* __restrict__ Wo, float* __restrict__ C) {
  __shared__ u16 As[2][64][40];
  __shared__ u16 Bs[2][32][72];
  const int tid  = threadIdx.x;
  const int lane = tid & 63;
  const int wave = tid >> 6;
  const long bm = (long)blockIdx.y * 64;
  const long bn = (long)blockIdx.x * 64;
  const int wm = (wave >> 1) * 32;
  const int wn_ = (wave & 1) * 32;
  const int ar = tid >> 2, ac = (tid & 3) * 8;
  const int br = tid >> 3, bc = (tid & 7) * 8;
  const int q = lane >> 4, r = lane & 15;
  const int N = HID, K = PP;
  floatx4 acc[2][2];
#pragma unroll
  for (int i = 0; i < 2; ++i)
#pragma unroll
    for (int j = 0; j < 2; ++j) acc[i][j] = (floatx4)0.f;

  for (int k0 = 0; k0 < K; k0 += 32) {
    u16 ahi[8], alo[8], bhi[8], blo[8];
    {
      long t = bm + ar;
      int c = k0 + ac;
      float ri = rinv[t * NH + (c >> 7)];
      const u16* op = ob + t * PP + c;
      const u16* gp = g2 + t * PP + c;
#pragma unroll
      for (int e = 0; e < 8; ++e) {
        float a = b2f(op[e]) * ri * wn[(c & 127) + e] * sigmoidf_(b2f(gp[e]));
        u16 hh = f2b(a);
        ahi[e] = hh;
        alo[e] = f2b(a - b2f(hh));
      }
      const float* bp = Wo + (long)(k0 + br) * N + bn + bc;
#pragma unroll
      for (int e = 0; e < 8; ++e) {
        float x = bp[e];
        u16 hh = f2b(x);
        bhi[e] = hh;
        blo[e] = f2b(x - b2f(hh));
      }
    }
    __syncthreads();
    *(float4*)&As[0][ar][ac] = *(float4*)ahi;
    *(float4*)&As[1][ar][ac] = *(float4*)alo;
    *(float4*)&Bs[0][br][bc] = *(float4*)bhi;
    *(float4*)&Bs[1][br][bc] = *(float4*)blo;
    __syncthreads();
    short8 afh[2], afl[2], bfh[2], bfl[2];
#pragma unroll
    for (int i = 0; i < 2; ++i) {
      afh[i] = *(const short8*)&As[0][wm + i * 16 + r][q * 8];
      afl[i] = *(const short8*)&As[1][wm + i * 16 + r][q * 8];
    }
#pragma unroll
    for (int i = 0; i < 2; ++i) {
      short8 th, tl;
#pragma unroll
      for (int j = 0; j < 8; ++j) {
        th[j] = (short)Bs[0][q * 8 + j][wn_ + i * 16 + r];
        tl[j] = (short)Bs[1][q * 8 + j][wn_ + i * 16 + r];
      }
      bfh[i] = th; bfl[i] = tl;
    }
#pragma unroll
    for (int i = 0; i < 2; ++i)
#pragma unroll
      for (int j = 0; j < 2; ++j) {
        acc[i][j] = __builtin_amdgcn_mfma_f32_16x16x32_bf16(afh[i], bfh[j], acc[i][j], 0, 0, 0);
        acc[i][j] = __builtin_amdgcn_mfma_f32_16x16x32_bf16(afh[i], bfl[j], acc[i][j], 0, 0, 0);
        acc[i][j] = __builtin_amdgcn_mfma_f32_16x16x32_bf16(afl[i], bfh[j], acc[i][j], 0, 0, 0);
      }
  }
#pragma unroll
  for (int i = 0; i < 2; ++i)
#pragma unroll
    for (int j = 0; j < 2; ++j) {
      long col = bn + wn_ + j * 16 + r;
#pragma unroll
      for (int e = 0; e < 4; ++e) {
        long row = bm + wm + i * 16 + q * 4 + e;
        C[row * N + col] = acc[i][j][e];
      }
    }
}

extern "C" void kernel_launch(void* const* d_in, const int* in_sizes, int n_in,
                              void* d_out, int out_size, void* d_ws, size_t ws_size,
                              hipStream_t stream) {
  const float* hs   = (const float*)d_in[0];
  const float* Wq   = (const float*)d_in[1];
  const float* Wk   = (const float*)d_in[2];
  const float* Wv   = (const float*)d_in[3];
  const float* cq   = (const float*)d_in[4];
  const float* ck   = (const float*)d_in[5];
  const float* cv   = (const float*)d_in[6];
  const float* Wb   = (const float*)d_in[7];
  const float* Wfa  = (const float*)d_in[8];
  const float* Wfb  = (const float*)d_in[9];
  const float* dtb  = (const float*)d_in[10];
  const float* Alog = (const float*)d_in[11];
  const float* Wga  = (const float*)d_in[12];
  const float* Wgb  = (const float*)d_in[13];
  const float* wn   = (const float*)d_in[14];
  const float* Wo   = (const float*)d_in[15];

  char* ws = (char*)d_ws;
  const size_t SZB = (size_t)T_TOK * PP * 2;     // 32 MiB per bf16 [T,P]
  u16*   B0   = (u16*)(ws + 0 * SZB);            // pre_q raw
  u16*   B1   = (u16*)(ws + 1 * SZB);            // pre_k raw; after scan: g2pre
  u16*   B2   = (u16*)(ws + 2 * SZB);            // pre_v raw -> o (in-place)
  u16*   B3   = (u16*)(ws + 3 * SZB);            // g1pre -> log-decay x
  float* beta = (float*)(ws + 4 * SZB);                      // 512 KiB
  float* rinv = (float*)(ws + 4 * SZB + (512u << 10));       // 512 KiB
  u16*   hfa  = (u16*)(ws + 4 * SZB + (1u << 20));           // [T,128] bf16, 1 MiB
  u16*   hga  = (u16*)(ws + 4 * SZB + (2u << 20));           // [T,128] bf16, 1 MiB
  // total extent: 128 MiB + 3 MiB = 131 MiB (identical to rounds 2/3, which ran)

  dim3 blk(256);
  dim3 g_big(PP / 64, T_TOK / 64);
  dim3 g_thin(HD / 64, T_TOK / 64);
  const int EW = T_TOK * PP / 256;

  // raw projections (split = fp32-quality), stored bf16
  gemm_k<0, 1, 1><<<g_big, blk, 0, stream>>>(hs, Wq, B0, T_TOK, PP, HID);
  gemm_k<0, 1, 1><<<g_big, blk, 0, stream>>>(hs, Wk, B1, T_TOK, PP, HID);
  gemm_k<0, 1, 1><<<g_big, blk, 0, stream>>>(hs, Wv, B2, T_TOK, PP, HID);
  // beta (fp32 scalar dot)
  beta_k<<<T_TOK / 8, blk, 0, stream>>>(hs, Wb, beta);
  // g1 path -> log-domain decay x in B3
  gemm_k<0, 1, 1><<<g_thin, blk, 0, stream>>>(hs, Wfa, hfa, T_TOK, HD, HID);
  gemm_k<1, 0, 1><<<g_big, blk, 0, stream>>>(hfa, Wfb, B3, T_TOK, PP, HD);
  expg_k<<<EW, blk, 0, stream>>>(B3, dtb, Alog);
  // g2 first stage
  gemm_k<0, 1, 1><<<g_thin, blk, 0, stream>>>(hs, Wga, hga, T_TOK, HD, HID);
  // fused conv+silu+scan (o -> B2 in place)
  scan_k<<<T_TOK / 4, blk, 0, stream>>>(B0, B1, B2, B3, beta, cq, ck, cv);
  // g2 second stage into freed B1
  gemm_k<1, 0, 1><<<g_big, blk, 0, stream>>>(hga, Wgb, B1, T_TOK, PP, HD);
  // rms factors
  rms_k<<<T_TOK * NH / 4, blk, 0, stream>>>(B2, rinv);
  // final projection with fused gated RMSNorm, fp32 out
  gemm_final_k<<<dim3(HID / 64, T_TOK / 64), blk, 0, stream>>>(B2, B1, rinv, wn, Wo, (float*)d_out);
}